// Round 14
// baseline (241.786 us; speedup 1.0000x reference)
//
#include <hip/hip_runtime.h>

typedef short short8 __attribute__((ext_vector_type(8)));
typedef float f32x4 __attribute__((ext_vector_type(4)));
typedef unsigned int u32x2 __attribute__((ext_vector_type(2)));
typedef unsigned int u32x4 __attribute__((ext_vector_type(4)));

#define N_NODES   100000
#define E_KEEP    1000000
#define E_TOTAL_N 1100000
#define EDGE_OUT_BASE 12800000L

#define H1_STRIDE 272
#define STG_STRIDE 272

__device__ __forceinline__ unsigned short f2bf(float f) {
  unsigned int u = __builtin_bit_cast(unsigned int, f);
  u += 0x7fffu + ((u >> 16) & 1u);
  return (unsigned short)(u >> 16);
}

// v_cvt_pk_bf16_f32 (acquitted R11): lo->bits[15:0], hi->bits[31:16], RNE
__device__ __forceinline__ unsigned int cvtpk(float lo, float hi) {
  unsigned int r;
  asm("v_cvt_pk_bf16_f32 %0, %1, %2" : "=v"(r) : "v"(lo), "v"(hi));
  return r;
}
__device__ __forceinline__ unsigned int pack2relu(float lo, float hi) {
  return cvtpk(fmaxf(lo, 0.f), fmaxf(hi, 0.f));
}

// nw2/ew2 fp32 [128][128] -> bf16 W2^T in ws (node [0:16384], edge [16384:32768])
__global__ void transpose_w2(const float* __restrict__ nw2,
                             const float* __restrict__ ew2,
                             unsigned short* __restrict__ ws) {
  int idx = blockIdx.x * 256 + threadIdx.x;
  for (int i = idx; i < 32768; i += 8192) {
    int m = i >> 14;
    int w = i & 16383;
    int k = w >> 7;
    int n = w & 127;
    const float* src = m ? ew2 : nw2;
    ws[m * 16384 + n * 128 + k] = f2bf(src[w]);  // W2T[n][k] = W2[k][n]
  }
}

struct SmemLayout {
  float w1f[7 * 128];      // layer-1 weights in LDS (NODE path only)
  float b1f[128];
  float b2f[128];
  float attr[256 * 7];     // per-row attrs: edge stride 4 (f32x4), node stride 7
  char  h1[2][32 * H1_STRIDE];   // double-buffered bf16 h1 tile
  char  stg[32 * STG_STRIDE];    // bf16 output stage tile
};

// R11 base (best: 163 us) + XCD swizzle + NT stores + b2-reg + attr-f32x4.
template<bool IS_EDGE>
__device__ __forceinline__ void run_path(
    const float* __restrict__ src,   // pos (edges) or x (nodes)
    const int* __restrict__ ei,
    const float* __restrict__ w1,
    const float* __restrict__ b1,
    const float* __restrict__ b2,
    const unsigned short* __restrict__ w2t,
    float* __restrict__ outp, long out_base, int row_limit,
    int bid, SmemLayout& sm)
{
  constexpr int NA = IS_EDGE ? 3 : 7;
  constexpr int ASTRIDE = IS_EDGE ? 4 : 7;
  const int t = threadIdx.x;

  if (t < 128) { sm.b1f[t] = b1[t]; sm.b2f[t] = b2[t]; }
  if (!IS_EDGE) {
    for (int i = t; i < 7 * 128; i += 256) sm.w1f[i] = w1[i];
  }

  // ---- phase A: attrs for this block's 256 rows (1 row per thread) ----
  {
    int r  = bid * 256 + t;
    int rl = r < row_limit ? r : row_limit - 1;
    if (IS_EDGE) {
      int si = ei[rl];
      int di = ei[E_TOTAL_N + rl];
      float ax = src[si * 3]     - src[di * 3];
      float ay = src[si * 3 + 1] - src[di * 3 + 1];
      f32x4 a4 = {ax, ay, sqrtf(ax * ax + ay * ay), 0.f};
      *(f32x4*)&sm.attr[t * 4] = a4;
    } else {
#pragma unroll
      for (int cc = 0; cc < 7; ++cc) sm.attr[t * 7 + cc] = src[rl * 7 + cc];
    }
  }

  const int lane = t & 63;
  const int wid  = t >> 6;
  const int rg   = wid & 1;
  const int wc   = wid >> 1;
  const int c    = lane & 15;
  const int g    = lane >> 4;

  // W2^T MFMA A-fragments (R2-proven): lane holds n = wc*64+nf*16+c, k = kk*32+g*8..+8
  short8 wfrag[4][4];
#pragma unroll
  for (int nf = 0; nf < 4; ++nf)
#pragma unroll
    for (int kk = 0; kk < 4; ++kk)
      wfrag[nf][kk] = *(const short8*)(w2t + (wc * 64 + nf * 16 + c) * 128 + kk * 32 + g * 8);

  // phase-B mapping: 32 rows x 8 k-chunks of 16 k.
  const int brow = t & 31;
  const int kc   = t >> 5;
  const int k0   = kc * 16;

  // EDGES: loop-invariant w1 slice from GLOBAL into regs (12 f32x4, L2-resident)
  f32x4 w1r[IS_EDGE ? 12 : 1];
  if (IS_EDGE) {
#pragma unroll
    for (int cc = 0; cc < 3; ++cc)
#pragma unroll
      for (int q = 0; q < 4; ++q)
        w1r[cc * 4 + q] = *(const f32x4*)&w1[cc * 128 + k0 + q * 4];
  }

  const int rrow = rg * 16 + c;     // phase-C tile-local row

  __syncthreads();   // attrs + LDS params visible

  // b2 slice in registers (phase-C epilogue; saves 4 b128 LDS reads/iter)
  f32x4 b2v[4];
#pragma unroll
  for (int nf = 0; nf < 4; ++nf)
    b2v[nf] = *(const f32x4*)&sm.b2f[wc * 64 + nf * 16 + g * 4];

  for (int s = 0; s < 8; ++s) {
    char* h1 = sm.h1[s & 1];

    // ---- phase B: h1 for 32 rows x 128 k, computed ONCE, -> padded LDS ----
    {
      float a[NA];
      if (IS_EDGE) {
        f32x4 a4 = *(const f32x4*)&sm.attr[(s * 32 + brow) * 4];
        a[0] = a4[0]; a[1] = a4[1]; a[2] = a4[2];
      } else {
#pragma unroll
        for (int cc = 0; cc < NA; ++cc)
          a[cc] = sm.attr[(s * 32 + brow) * ASTRIDE + cc];
      }

      f32x4 h0 = *(const f32x4*)&sm.b1f[k0];
      f32x4 h1v = *(const f32x4*)&sm.b1f[k0 + 4];
      f32x4 h2 = *(const f32x4*)&sm.b1f[k0 + 8];
      f32x4 h3 = *(const f32x4*)&sm.b1f[k0 + 12];
      if (IS_EDGE) {
#pragma unroll
        for (int cc = 0; cc < 3; ++cc) {
          h0  += a[cc] * w1r[cc * 4 + 0];
          h1v += a[cc] * w1r[cc * 4 + 1];
          h2  += a[cc] * w1r[cc * 4 + 2];
          h3  += a[cc] * w1r[cc * 4 + 3];
        }
      } else {
#pragma unroll
        for (int cc = 0; cc < NA; ++cc) {
          h0  += a[cc] * *(const f32x4*)&sm.w1f[cc * 128 + k0];
          h1v += a[cc] * *(const f32x4*)&sm.w1f[cc * 128 + k0 + 4];
          h2  += a[cc] * *(const f32x4*)&sm.w1f[cc * 128 + k0 + 8];
          h3  += a[cc] * *(const f32x4*)&sm.w1f[cc * 128 + k0 + 12];
        }
      }
      u32x4 dA, dB;
      dA[0] = pack2relu(h0[0], h0[1]);  dA[1] = pack2relu(h0[2], h0[3]);
      dA[2] = pack2relu(h1v[0], h1v[1]); dA[3] = pack2relu(h1v[2], h1v[3]);
      dB[0] = pack2relu(h2[0], h2[1]);  dB[1] = pack2relu(h2[2], h2[3]);
      dB[2] = pack2relu(h3[0], h3[1]);  dB[3] = pack2relu(h3[2], h3[3]);

      char* wp = h1 + brow * H1_STRIDE + kc * 32;
      *(u32x4*)(wp)      = dA;
      *(u32x4*)(wp + 16) = dB;
    }

    __syncthreads();   // bar1: h1 ready; also orders stg WAR

    // ---- phase C: MFMA, then pack acc+b2 -> bf16 stage tile ----
    {
      f32x4 acc0 = {}, acc1 = {}, acc2 = {}, acc3 = {};
#pragma unroll
      for (int kk = 0; kk < 4; ++kk) {
        short8 hf = *(const short8*)(h1 + rrow * H1_STRIDE + kk * 64 + g * 16);
        acc0 = __builtin_amdgcn_mfma_f32_16x16x32_bf16(wfrag[0][kk], hf, acc0, 0, 0, 0);
        acc1 = __builtin_amdgcn_mfma_f32_16x16x32_bf16(wfrag[1][kk], hf, acc1, 0, 0, 0);
        acc2 = __builtin_amdgcn_mfma_f32_16x16x32_bf16(wfrag[2][kk], hf, acc2, 0, 0, 0);
        acc3 = __builtin_amdgcn_mfma_f32_16x16x32_bf16(wfrag[3][kk], hf, acc3, 0, 0, 0);
      }
      char* wp = sm.stg + rrow * STG_STRIDE + (wc * 64 + g * 4) * 2;
      f32x4 av[4] = {acc0 + b2v[0], acc1 + b2v[1], acc2 + b2v[2], acc3 + b2v[3]};
#pragma unroll
      for (int nf = 0; nf < 4; ++nf) {
        u32x2 d;
        d[0] = cvtpk(av[nf][0], av[nf][1]);
        d[1] = cvtpk(av[nf][2], av[nf][3]);
        *(u32x2*)(wp + nf * 32) = d;
      }
    }

    __syncthreads();   // bar2: stage ready

    // ---- phase C': linear stage read -> full-line NONTEMPORAL f32 stores ----
    {
      int r0 = bid * 256 + s * 32;
#pragma unroll
      for (int p = 0; p < 2; ++p) {
        int u   = p * 256 + t;
        int row = u >> 4;
        int k16 = u & 15;
        if (r0 + row < row_limit) {
          short8 v = *(const short8*)(sm.stg + row * STG_STRIDE + k16 * 16);
          f32x4 lo, hi;
#pragma unroll
          for (int j = 0; j < 4; ++j) {
            lo[j] = __builtin_bit_cast(float, ((unsigned int)(unsigned short)v[j]) << 16);
            hi[j] = __builtin_bit_cast(float, ((unsigned int)(unsigned short)v[4 + j]) << 16);
          }
          float* op = outp + out_base + (long)(r0 + row) * 128 + k16 * 8;
          __builtin_nontemporal_store(lo, (f32x4*)op);
          __builtin_nontemporal_store(hi, (f32x4*)(op + 4));
        }
      }
    }
  }
}

__global__ __launch_bounds__(256, 3) void encoder_kernel(
    const float* __restrict__ x,
    const float* __restrict__ pos,
    const int* __restrict__ ei,
    const float* __restrict__ nw1,
    const float* __restrict__ nb1,
    const float* __restrict__ nb2,
    const float* __restrict__ ew1,
    const float* __restrict__ eb1,
    const float* __restrict__ eb2,
    const unsigned short* __restrict__ ws,
    float* __restrict__ outp,
    int nodeBlocks, int totalBlocks)
{
  __shared__ SmemLayout sm;
  // Bijective XCD swizzle (m204 form; totalBlocks need not be %8):
  // each XCD gets a CONTIGUOUS bid chunk -> contiguous output span per L2.
  int orig = blockIdx.x;
  int q = totalBlocks >> 3, r = totalBlocks & 7;
  int xcd = orig & 7, idx = orig >> 3;
  int bid = (xcd < r ? xcd * (q + 1) : r * (q + 1) + (xcd - r) * q) + idx;

  if (bid < nodeBlocks) {
    run_path<false>(x, nullptr, nw1, nb1, nb2, ws, outp, 0L, N_NODES, bid, sm);
  } else {
    run_path<true>(pos, ei, ew1, eb1, eb2, ws + 16384, outp, EDGE_OUT_BASE,
                   E_KEEP, bid - nodeBlocks, sm);
  }
}

extern "C" void kernel_launch(void* const* d_in, const int* in_sizes, int n_in,
                              void* d_out, int out_size, void* d_ws, size_t ws_size,
                              hipStream_t stream) {
  const float* x   = (const float*)d_in[0];
  const float* pos = (const float*)d_in[1];
  const int*   ei  = (const int*)d_in[2];
  const float* nw1 = (const float*)d_in[3];
  const float* nb1 = (const float*)d_in[4];
  const float* nw2 = (const float*)d_in[5];
  const float* nb2 = (const float*)d_in[6];
  const float* ew1 = (const float*)d_in[7];
  const float* eb1 = (const float*)d_in[8];
  const float* ew2 = (const float*)d_in[9];
  const float* eb2 = (const float*)d_in[10];
  unsigned short* ws   = (unsigned short*)d_ws;
  float*          outp = (float*)d_out;

  transpose_w2<<<32, 256, 0, stream>>>(nw2, ew2, ws);

  int nodeBlocks = (N_NODES + 255) / 256;  // 391
  int edgeBlocks = (E_KEEP + 255) / 256;   // 3907
  int totalBlocks = nodeBlocks + edgeBlocks;
  encoder_kernel<<<totalBlocks, 256, 0, stream>>>(
      x, pos, ei, nw1, nb1, nb2, ew1, eb1, eb2, ws, outp, nodeBlocks, totalBlocks);
}

// Round 15
// 175.347 us; speedup vs baseline: 1.3789x; 1.3789x over previous
//
#include <hip/hip_runtime.h>

typedef short short8 __attribute__((ext_vector_type(8)));
typedef float f32x4 __attribute__((ext_vector_type(4)));
typedef unsigned int u32x2 __attribute__((ext_vector_type(2)));
typedef unsigned int u32x4 __attribute__((ext_vector_type(4)));

#define N_NODES   100000
#define E_KEEP    1000000
#define E_TOTAL_N 1100000
#define EDGE_OUT_BASE 12800000L

#define H1_STRIDE 272
#define STG_STRIDE 272

__device__ __forceinline__ unsigned short f2bf(float f) {
  unsigned int u = __builtin_bit_cast(unsigned int, f);
  u += 0x7fffu + ((u >> 16) & 1u);   // round-to-nearest-even
  return (unsigned short)(u >> 16);
}

// v_cvt_pk_bf16_f32 (acquitted R11): lo->bits[15:0], hi->bits[31:16], RNE
__device__ __forceinline__ unsigned int cvtpk(float lo, float hi) {
  unsigned int r;
  asm("v_cvt_pk_bf16_f32 %0, %1, %2" : "=v"(r) : "v"(lo), "v"(hi));
  return r;
}
__device__ __forceinline__ unsigned int pack2relu(float lo, float hi) {
  return cvtpk(fmaxf(lo, 0.f), fmaxf(hi, 0.f));
}
__device__ __forceinline__ unsigned int pack2(float lo, float hi) {
  return cvtpk(lo, hi);
}

// nw2/ew2 fp32 [128][128] -> bf16 W2^T in ws (node [0:16384], edge [16384:32768])
__global__ void transpose_w2(const float* __restrict__ nw2,
                             const float* __restrict__ ew2,
                             unsigned short* __restrict__ ws) {
  int idx = blockIdx.x * 256 + threadIdx.x;
  for (int i = idx; i < 32768; i += 8192) {
    int m = i >> 14;
    int w = i & 16383;
    int k = w >> 7;
    int n = w & 127;
    const float* src = m ? ew2 : nw2;
    ws[m * 16384 + n * 128 + k] = f2bf(src[w]);  // W2T[n][k] = W2[k][n]
  }
}

struct SmemLayout {
  float w1f[7 * 128];      // layer-1 weights in LDS (NODE path only)
  float b1f[128];
  float b2f[128];
  float attr[256 * 7];     // per-row attrs, natural stride NA (3 or 7)
  char  h1[2][32 * H1_STRIDE];   // double-buffered bf16 h1 tile
  char  stg[32 * STG_STRIDE];    // bf16 output stage tile
};

// VERBATIM R11 structure (best: 163 us). Single new lever: XCD swizzle.
template<bool IS_EDGE>
__device__ __forceinline__ void run_path(
    const float* __restrict__ src,   // pos (edges) or x (nodes)
    const int* __restrict__ ei,
    const float* __restrict__ w1,
    const float* __restrict__ b1,
    const float* __restrict__ b2,
    const unsigned short* __restrict__ w2t,
    float* __restrict__ outp, long out_base, int row_limit,
    int bid, SmemLayout& sm)
{
  constexpr int NA = IS_EDGE ? 3 : 7;
  const int t = threadIdx.x;

  if (t < 128) { sm.b1f[t] = b1[t]; sm.b2f[t] = b2[t]; }
  if (!IS_EDGE) {
    for (int i = t; i < 7 * 128; i += 256) sm.w1f[i] = w1[i];
  }

  // ---- phase A: attrs for this block's 256 rows (1 row per thread) ----
  {
    int r  = bid * 256 + t;
    int rl = r < row_limit ? r : row_limit - 1;
    if (IS_EDGE) {
      int si = ei[rl];
      int di = ei[E_TOTAL_N + rl];
      float ax = src[si * 3]     - src[di * 3];
      float ay = src[si * 3 + 1] - src[di * 3 + 1];
      sm.attr[t * 3 + 0] = ax;
      sm.attr[t * 3 + 1] = ay;
      sm.attr[t * 3 + 2] = sqrtf(ax * ax + ay * ay);
    } else {
#pragma unroll
      for (int cc = 0; cc < 7; ++cc) sm.attr[t * 7 + cc] = src[rl * 7 + cc];
    }
  }

  const int lane = t & 63;
  const int wid  = t >> 6;
  const int rg   = wid & 1;
  const int wc   = wid >> 1;
  const int c    = lane & 15;
  const int g    = lane >> 4;

  // W2^T MFMA A-fragments (R2-proven): lane holds n = wc*64+nf*16+c, k = kk*32+g*8..+8
  short8 wfrag[4][4];
#pragma unroll
  for (int nf = 0; nf < 4; ++nf)
#pragma unroll
    for (int kk = 0; kk < 4; ++kk)
      wfrag[nf][kk] = *(const short8*)(w2t + (wc * 64 + nf * 16 + c) * 128 + kk * 32 + g * 8);

  // phase-B mapping: 32 rows x 8 k-chunks of 16 k.
  const int brow = t & 31;
  const int kc   = t >> 5;
  const int k0   = kc * 16;

  // EDGES: hoist this thread's loop-invariant w1 slice from GLOBAL into regs
  f32x4 w1r[IS_EDGE ? 12 : 1];
  if (IS_EDGE) {
#pragma unroll
    for (int cc = 0; cc < 3; ++cc)
#pragma unroll
      for (int q = 0; q < 4; ++q)
        w1r[cc * 4 + q] = *(const f32x4*)&w1[cc * 128 + k0 + q * 4];
  }

  const int rrow = rg * 16 + c;     // phase-C tile-local row

  __syncthreads();   // attrs + LDS params visible

  for (int s = 0; s < 8; ++s) {
    char* h1 = sm.h1[s & 1];

    // ---- phase B: h1 for 32 rows x 128 k, computed ONCE, -> padded LDS ----
    {
      float a[NA];
#pragma unroll
      for (int cc = 0; cc < NA; ++cc) a[cc] = sm.attr[(s * 32 + brow) * NA + cc];

      f32x4 h0 = *(const f32x4*)&sm.b1f[k0];
      f32x4 h1v = *(const f32x4*)&sm.b1f[k0 + 4];
      f32x4 h2 = *(const f32x4*)&sm.b1f[k0 + 8];
      f32x4 h3 = *(const f32x4*)&sm.b1f[k0 + 12];
      if (IS_EDGE) {
#pragma unroll
        for (int cc = 0; cc < 3; ++cc) {
          h0  += a[cc] * w1r[cc * 4 + 0];
          h1v += a[cc] * w1r[cc * 4 + 1];
          h2  += a[cc] * w1r[cc * 4 + 2];
          h3  += a[cc] * w1r[cc * 4 + 3];
        }
      } else {
#pragma unroll
        for (int cc = 0; cc < NA; ++cc) {
          h0  += a[cc] * *(const f32x4*)&sm.w1f[cc * 128 + k0];
          h1v += a[cc] * *(const f32x4*)&sm.w1f[cc * 128 + k0 + 4];
          h2  += a[cc] * *(const f32x4*)&sm.w1f[cc * 128 + k0 + 8];
          h3  += a[cc] * *(const f32x4*)&sm.w1f[cc * 128 + k0 + 12];
        }
      }
      u32x4 dA, dB;
      dA[0] = pack2relu(h0[0], h0[1]);  dA[1] = pack2relu(h0[2], h0[3]);
      dA[2] = pack2relu(h1v[0], h1v[1]); dA[3] = pack2relu(h1v[2], h1v[3]);
      dB[0] = pack2relu(h2[0], h2[1]);  dB[1] = pack2relu(h2[2], h2[3]);
      dB[2] = pack2relu(h3[0], h3[1]);  dB[3] = pack2relu(h3[2], h3[3]);

      char* wp = h1 + brow * H1_STRIDE + kc * 32;
      *(u32x4*)(wp)      = dA;
      *(u32x4*)(wp + 16) = dB;
    }

    __syncthreads();   // bar1: h1 ready; also orders stg WAR

    // ---- phase C: MFMA, then pack acc+b2 -> bf16 stage tile ----
    {
      f32x4 acc0 = {}, acc1 = {}, acc2 = {}, acc3 = {};
#pragma unroll
      for (int kk = 0; kk < 4; ++kk) {
        short8 hf = *(const short8*)(h1 + rrow * H1_STRIDE + kk * 64 + g * 16);
        acc0 = __builtin_amdgcn_mfma_f32_16x16x32_bf16(wfrag[0][kk], hf, acc0, 0, 0, 0);
        acc1 = __builtin_amdgcn_mfma_f32_16x16x32_bf16(wfrag[1][kk], hf, acc1, 0, 0, 0);
        acc2 = __builtin_amdgcn_mfma_f32_16x16x32_bf16(wfrag[2][kk], hf, acc2, 0, 0, 0);
        acc3 = __builtin_amdgcn_mfma_f32_16x16x32_bf16(wfrag[3][kk], hf, acc3, 0, 0, 0);
      }
      char* wp = sm.stg + rrow * STG_STRIDE + (wc * 64 + g * 4) * 2;
      f32x4 av[4] = {acc0, acc1, acc2, acc3};
#pragma unroll
      for (int nf = 0; nf < 4; ++nf) {
        f32x4 bv = *(const f32x4*)&sm.b2f[wc * 64 + nf * 16 + g * 4];
        f32x4 o = av[nf] + bv;
        u32x2 d;
        d[0] = pack2(o[0], o[1]);
        d[1] = pack2(o[2], o[3]);
        *(u32x2*)(wp + nf * 32) = d;
      }
    }

    __syncthreads();   // bar2: stage ready

    // ---- phase C': linear stage read -> full-line coalesced f32 stores ----
    {
      int r0 = bid * 256 + s * 32;
#pragma unroll
      for (int p = 0; p < 2; ++p) {
        int u   = p * 256 + t;
        int row = u >> 4;
        int k16 = u & 15;
        if (r0 + row < row_limit) {
          short8 v = *(const short8*)(sm.stg + row * STG_STRIDE + k16 * 16);
          f32x4 lo, hi;
#pragma unroll
          for (int j = 0; j < 4; ++j) {
            lo[j] = __builtin_bit_cast(float, ((unsigned int)(unsigned short)v[j]) << 16);
            hi[j] = __builtin_bit_cast(float, ((unsigned int)(unsigned short)v[4 + j]) << 16);
          }
          float* op = outp + out_base + (long)(r0 + row) * 128 + k16 * 8;
          *(f32x4*)op       = lo;
          *(f32x4*)(op + 4) = hi;
        }
      }
    }
  }
}

__global__ __launch_bounds__(256, 3) void encoder_kernel(
    const float* __restrict__ x,
    const float* __restrict__ pos,
    const int* __restrict__ ei,
    const float* __restrict__ nw1,
    const float* __restrict__ nb1,
    const float* __restrict__ nb2,
    const float* __restrict__ ew1,
    const float* __restrict__ eb1,
    const float* __restrict__ eb2,
    const unsigned short* __restrict__ ws,
    float* __restrict__ outp,
    int nodeBlocks, int totalBlocks)
{
  __shared__ SmemLayout sm;
  // Bijective XCD swizzle (m204): each XCD gets a CONTIGUOUS bid chunk.
  int orig = blockIdx.x;
  int q = totalBlocks >> 3, r = totalBlocks & 7;
  int xcd = orig & 7, idx = orig >> 3;
  int bid = (xcd < r ? xcd * (q + 1) : r * (q + 1) + (xcd - r) * q) + idx;

  if (bid < nodeBlocks) {
    run_path<false>(x, nullptr, nw1, nb1, nb2, ws, outp, 0L, N_NODES, bid, sm);
  } else {
    run_path<true>(pos, ei, ew1, eb1, eb2, ws + 16384, outp, EDGE_OUT_BASE,
                   E_KEEP, bid - nodeBlocks, sm);
  }
}

extern "C" void kernel_launch(void* const* d_in, const int* in_sizes, int n_in,
                              void* d_out, int out_size, void* d_ws, size_t ws_size,
                              hipStream_t stream) {
  const float* x   = (const float*)d_in[0];
  const float* pos = (const float*)d_in[1];
  const int*   ei  = (const int*)d_in[2];
  const float* nw1 = (const float*)d_in[3];
  const float* nb1 = (const float*)d_in[4];
  const float* nw2 = (const float*)d_in[5];
  const float* nb2 = (const float*)d_in[6];
  const float* ew1 = (const float*)d_in[7];
  const float* eb1 = (const float*)d_in[8];
  const float* ew2 = (const float*)d_in[9];
  const float* eb2 = (const float*)d_in[10];
  unsigned short* ws   = (unsigned short*)d_ws;
  float*          outp = (float*)d_out;

  transpose_w2<<<32, 256, 0, stream>>>(nw2, ew2, ws);

  int nodeBlocks = (N_NODES + 255) / 256;  // 391
  int edgeBlocks = (E_KEEP + 255) / 256;   // 3907
  int totalBlocks = nodeBlocks + edgeBlocks;
  encoder_kernel<<<totalBlocks, 256, 0, stream>>>(
      x, pos, ei, nw1, nb1, nb2, ew1, eb1, eb2, ws, outp, nodeBlocks, totalBlocks);
}

// Round 16
// 162.961 us; speedup vs baseline: 1.4837x; 1.0760x over previous
//
#include <hip/hip_runtime.h>

typedef short short8 __attribute__((ext_vector_type(8)));
typedef float f32x4 __attribute__((ext_vector_type(4)));
typedef unsigned int u32x2 __attribute__((ext_vector_type(2)));
typedef unsigned int u32x4 __attribute__((ext_vector_type(4)));

#define N_NODES   100000
#define E_KEEP    1000000
#define E_TOTAL_N 1100000
#define EDGE_OUT_BASE 12800000L

#define H1_STRIDE 272
#define STG_STRIDE 272

__device__ __forceinline__ unsigned short f2bf(float f) {
  unsigned int u = __builtin_bit_cast(unsigned int, f);
  u += 0x7fffu + ((u >> 16) & 1u);   // round-to-nearest-even
  return (unsigned short)(u >> 16);
}

// v_cvt_pk_bf16_f32: lo -> bits[15:0], hi -> bits[31:16], RNE.
__device__ __forceinline__ unsigned int cvtpk(float lo, float hi) {
  unsigned int r;
  asm("v_cvt_pk_bf16_f32 %0, %1, %2" : "=v"(r) : "v"(lo), "v"(hi));
  return r;
}
__device__ __forceinline__ unsigned int pack2relu(float lo, float hi) {
  return cvtpk(fmaxf(lo, 0.f), fmaxf(hi, 0.f));
}
__device__ __forceinline__ unsigned int pack2(float lo, float hi) {
  return cvtpk(lo, hi);
}

// nw2/ew2 fp32 [128][128] -> bf16 W2^T in ws (node [0:16384], edge [16384:32768])
__global__ void transpose_w2(const float* __restrict__ nw2,
                             const float* __restrict__ ew2,
                             unsigned short* __restrict__ ws) {
  int idx = blockIdx.x * 256 + threadIdx.x;
  for (int i = idx; i < 32768; i += 8192) {
    int m = i >> 14;
    int w = i & 16383;
    int k = w >> 7;
    int n = w & 127;
    const float* src = m ? ew2 : nw2;
    ws[m * 16384 + n * 128 + k] = f2bf(src[w]);  // W2T[n][k] = W2[k][n]
  }
}

struct SmemLayout {
  float w1f[7 * 128];      // layer-1 weights in LDS (NODE path only)
  float b1f[128];
  float b2f[128];
  float attr[256 * 7];     // per-row attrs, natural stride NA (3 or 7)
  char  h1[2][32 * H1_STRIDE];   // double-buffered bf16 h1 tile
  char  stg[32 * STG_STRIDE];    // bf16 output stage tile
};

// Best variant (R11, 163 us): phase A gather-once, phase B layer-1-once ->
// padded LDS (conflict-free), phase C MFMA + bf16 stage, phase C' full-line
// coalesced stores. Edge w1 slice hoisted from GLOBAL to regs; cvt_pk packs.
template<bool IS_EDGE>
__device__ __forceinline__ void run_path(
    const float* __restrict__ src,   // pos (edges) or x (nodes)
    const int* __restrict__ ei,
    const float* __restrict__ w1,
    const float* __restrict__ b1,
    const float* __restrict__ b2,
    const unsigned short* __restrict__ w2t,
    float* __restrict__ outp, long out_base, int row_limit,
    int bid, SmemLayout& sm)
{
  constexpr int NA = IS_EDGE ? 3 : 7;
  const int t = threadIdx.x;

  if (t < 128) { sm.b1f[t] = b1[t]; sm.b2f[t] = b2[t]; }
  if (!IS_EDGE) {
    for (int i = t; i < 7 * 128; i += 256) sm.w1f[i] = w1[i];
  }

  // ---- phase A: attrs for this block's 256 rows (1 row per thread) ----
  {
    int r  = bid * 256 + t;
    int rl = r < row_limit ? r : row_limit - 1;
    if (IS_EDGE) {
      int si = ei[rl];
      int di = ei[E_TOTAL_N + rl];
      float ax = src[si * 3]     - src[di * 3];
      float ay = src[si * 3 + 1] - src[di * 3 + 1];
      sm.attr[t * 3 + 0] = ax;
      sm.attr[t * 3 + 1] = ay;
      sm.attr[t * 3 + 2] = sqrtf(ax * ax + ay * ay);
    } else {
#pragma unroll
      for (int cc = 0; cc < 7; ++cc) sm.attr[t * 7 + cc] = src[rl * 7 + cc];
    }
  }

  const int lane = t & 63;
  const int wid  = t >> 6;
  const int rg   = wid & 1;
  const int wc   = wid >> 1;
  const int c    = lane & 15;
  const int g    = lane >> 4;

  // W2^T MFMA A-fragments (R2-proven): lane holds n = wc*64+nf*16+c, k = kk*32+g*8..+8
  short8 wfrag[4][4];
#pragma unroll
  for (int nf = 0; nf < 4; ++nf)
#pragma unroll
    for (int kk = 0; kk < 4; ++kk)
      wfrag[nf][kk] = *(const short8*)(w2t + (wc * 64 + nf * 16 + c) * 128 + kk * 32 + g * 8);

  // phase-B mapping: 32 rows x 8 k-chunks of 16 k.
  const int brow = t & 31;
  const int kc   = t >> 5;
  const int k0   = kc * 16;

  // EDGES: hoist this thread's loop-invariant w1 slice from GLOBAL into regs
  f32x4 w1r[IS_EDGE ? 12 : 1];
  if (IS_EDGE) {
#pragma unroll
    for (int cc = 0; cc < 3; ++cc)
#pragma unroll
      for (int q = 0; q < 4; ++q)
        w1r[cc * 4 + q] = *(const f32x4*)&w1[cc * 128 + k0 + q * 4];
  }

  const int rrow = rg * 16 + c;     // phase-C tile-local row

  __syncthreads();   // attrs + LDS params visible

  for (int s = 0; s < 8; ++s) {
    char* h1 = sm.h1[s & 1];

    // ---- phase B: h1 for 32 rows x 128 k, computed ONCE, -> padded LDS ----
    {
      float a[NA];
#pragma unroll
      for (int cc = 0; cc < NA; ++cc) a[cc] = sm.attr[(s * 32 + brow) * NA + cc];

      f32x4 h0 = *(const f32x4*)&sm.b1f[k0];
      f32x4 h1v = *(const f32x4*)&sm.b1f[k0 + 4];
      f32x4 h2 = *(const f32x4*)&sm.b1f[k0 + 8];
      f32x4 h3 = *(const f32x4*)&sm.b1f[k0 + 12];
      if (IS_EDGE) {
#pragma unroll
        for (int cc = 0; cc < 3; ++cc) {
          h0  += a[cc] * w1r[cc * 4 + 0];
          h1v += a[cc] * w1r[cc * 4 + 1];
          h2  += a[cc] * w1r[cc * 4 + 2];
          h3  += a[cc] * w1r[cc * 4 + 3];
        }
      } else {
#pragma unroll
        for (int cc = 0; cc < NA; ++cc) {
          h0  += a[cc] * *(const f32x4*)&sm.w1f[cc * 128 + k0];
          h1v += a[cc] * *(const f32x4*)&sm.w1f[cc * 128 + k0 + 4];
          h2  += a[cc] * *(const f32x4*)&sm.w1f[cc * 128 + k0 + 8];
          h3  += a[cc] * *(const f32x4*)&sm.w1f[cc * 128 + k0 + 12];
        }
      }
      u32x4 dA, dB;
      dA[0] = pack2relu(h0[0], h0[1]);  dA[1] = pack2relu(h0[2], h0[3]);
      dA[2] = pack2relu(h1v[0], h1v[1]); dA[3] = pack2relu(h1v[2], h1v[3]);
      dB[0] = pack2relu(h2[0], h2[1]);  dB[1] = pack2relu(h2[2], h2[3]);
      dB[2] = pack2relu(h3[0], h3[1]);  dB[3] = pack2relu(h3[2], h3[3]);

      char* wp = h1 + brow * H1_STRIDE + kc * 32;
      *(u32x4*)(wp)      = dA;
      *(u32x4*)(wp + 16) = dB;
    }

    __syncthreads();   // bar1: h1 ready; also orders stg WAR

    // ---- phase C: MFMA, then pack acc+b2 -> bf16 stage tile ----
    {
      f32x4 acc0 = {}, acc1 = {}, acc2 = {}, acc3 = {};
#pragma unroll
      for (int kk = 0; kk < 4; ++kk) {
        short8 hf = *(const short8*)(h1 + rrow * H1_STRIDE + kk * 64 + g * 16);
        acc0 = __builtin_amdgcn_mfma_f32_16x16x32_bf16(wfrag[0][kk], hf, acc0, 0, 0, 0);
        acc1 = __builtin_amdgcn_mfma_f32_16x16x32_bf16(wfrag[1][kk], hf, acc1, 0, 0, 0);
        acc2 = __builtin_amdgcn_mfma_f32_16x16x32_bf16(wfrag[2][kk], hf, acc2, 0, 0, 0);
        acc3 = __builtin_amdgcn_mfma_f32_16x16x32_bf16(wfrag[3][kk], hf, acc3, 0, 0, 0);
      }
      char* wp = sm.stg + rrow * STG_STRIDE + (wc * 64 + g * 4) * 2;
      f32x4 av[4] = {acc0, acc1, acc2, acc3};
#pragma unroll
      for (int nf = 0; nf < 4; ++nf) {
        f32x4 bv = *(const f32x4*)&sm.b2f[wc * 64 + nf * 16 + g * 4];
        f32x4 o = av[nf] + bv;
        u32x2 d;
        d[0] = pack2(o[0], o[1]);
        d[1] = pack2(o[2], o[3]);
        *(u32x2*)(wp + nf * 32) = d;
      }
    }

    __syncthreads();   // bar2: stage ready

    // ---- phase C': linear stage read -> full-line coalesced f32 stores ----
    {
      int r0 = bid * 256 + s * 32;
#pragma unroll
      for (int p = 0; p < 2; ++p) {
        int u   = p * 256 + t;
        int row = u >> 4;
        int k16 = u & 15;
        if (r0 + row < row_limit) {
          short8 v = *(const short8*)(sm.stg + row * STG_STRIDE + k16 * 16);
          f32x4 lo, hi;
#pragma unroll
          for (int j = 0; j < 4; ++j) {
            lo[j] = __builtin_bit_cast(float, ((unsigned int)(unsigned short)v[j]) << 16);
            hi[j] = __builtin_bit_cast(float, ((unsigned int)(unsigned short)v[4 + j]) << 16);
          }
          float* op = outp + out_base + (long)(r0 + row) * 128 + k16 * 8;
          *(f32x4*)op       = lo;
          *(f32x4*)(op + 4) = hi;
        }
      }
    }
  }
}

__global__ __launch_bounds__(256, 3) void encoder_kernel(
    const float* __restrict__ x,
    const float* __restrict__ pos,
    const int* __restrict__ ei,
    const float* __restrict__ nw1,
    const float* __restrict__ nb1,
    const float* __restrict__ nb2,
    const float* __restrict__ ew1,
    const float* __restrict__ eb1,
    const float* __restrict__ eb2,
    const unsigned short* __restrict__ ws,
    float* __restrict__ outp,
    int nodeBlocks)
{
  __shared__ SmemLayout sm;
  int bid = blockIdx.x;
  if (bid < nodeBlocks) {
    run_path<false>(x, nullptr, nw1, nb1, nb2, ws, outp, 0L, N_NODES, bid, sm);
  } else {
    run_path<true>(pos, ei, ew1, eb1, eb2, ws + 16384, outp, EDGE_OUT_BASE,
                   E_KEEP, bid - nodeBlocks, sm);
  }
}

extern "C" void kernel_launch(void* const* d_in, const int* in_sizes, int n_in,
                              void* d_out, int out_size, void* d_ws, size_t ws_size,
                              hipStream_t stream) {
  const float* x   = (const float*)d_in[0];
  const float* pos = (const float*)d_in[1];
  const int*   ei  = (const int*)d_in[2];
  const float* nw1 = (const float*)d_in[3];
  const float* nb1 = (const float*)d_in[4];
  const float* nw2 = (const float*)d_in[5];
  const float* nb2 = (const float*)d_in[6];
  const float* ew1 = (const float*)d_in[7];
  const float* eb1 = (const float*)d_in[8];
  const float* ew2 = (const float*)d_in[9];
  const float* eb2 = (const float*)d_in[10];
  unsigned short* ws   = (unsigned short*)d_ws;
  float*          outp = (float*)d_out;

  transpose_w2<<<32, 256, 0, stream>>>(nw2, ew2, ws);

  int nodeBlocks = (N_NODES + 255) / 256;  // 391
  int edgeBlocks = (E_KEEP + 255) / 256;   // 3907
  encoder_kernel<<<nodeBlocks + edgeBlocks, 256, 0, stream>>>(
      x, pos, ei, nw1, nb1, nb2, ew1, eb1, eb2, ws, outp, nodeBlocks);
}